// Round 19
// baseline (306.497 us; speedup 1.0000x reference)
//
#include <hip/hip_runtime.h>

#define B_      8
#define N_      1024
#define DIN_    64
#define H_      128
#define MSG2    128
#define L_      5
#define TGT_    12
#define NLAYERS_ 3
#define CAT_    640          // L_ * MSG2
#define NODES   (B_ * N_)    // 8192
#define KSPLIT  4

typedef __attribute__((ext_vector_type(8))) short s16x8;
typedef __attribute__((ext_vector_type(4))) float f32x4;

__device__ __forceinline__ float sigmoidf_(float x) { return 1.f / (1.f + __expf(-x)); }

__device__ __forceinline__ unsigned short f2bf(float x) {
  unsigned int u = __float_as_uint(x);
  u += 0x7FFFu + ((u >> 16) & 1u);      // round-to-nearest-even
  return (unsigned short)(u >> 16);
}
__device__ __forceinline__ float bf2f(unsigned short u) {
  return __uint_as_float(((unsigned int)u) << 16);
}

// ---------------- merged prep: init | aprep | wprep ----------------
__global__ __launch_bounds__(256) void k_prep(const float* __restrict__ h_in,
                                              const float* __restrict__ A,
                                              const float* __restrict__ Wi,
                                              const float* __restrict__ Wh,
                                              float* __restrict__ h,
                                              float* __restrict__ h0,
                                              unsigned short* __restrict__ X,
                                              float* __restrict__ maskA,
                                              float* __restrict__ maskR,
                                              unsigned short* __restrict__ ATh,
                                              unsigned short* __restrict__ ATl,
                                              unsigned short* __restrict__ WiTh,
                                              unsigned short* __restrict__ WiTl,
                                              unsigned short* __restrict__ WhTh,
                                              unsigned short* __restrict__ WhTl) {
  const int blk = blockIdx.x;
  if (blk < NODES / 4) {
    int node = blk * 4 + (threadIdx.x >> 6);
    int lane = threadIdx.x & 63;
    float v = h_in[(size_t)node * DIN_ + lane];
    size_t base = (size_t)node * H_;
    h[base + lane] = v;   h[base + 64 + lane] = 0.f;
    h0[base + lane] = v;  h0[base + 64 + lane] = 0.f;
    unsigned short hi = f2bf(v);
    unsigned short lo = f2bf(v - bf2f(hi));
    size_t xb = (size_t)node * 256;
    X[xb + lane] = hi;        X[xb + 64 + lane] = 0;
    X[xb + 128 + lane] = lo;  X[xb + 192 + lane] = 0;
    float sa = fabsf(v), ss = v;
    for (int off = 32; off > 0; off >>= 1) {
      sa += __shfl_down(sa, off);
      ss += __shfl_down(ss, off);
    }
    if (lane == 0) {
      maskA[node] = (sa > 0.f) ? 1.f : 0.f;
      maskR[node] = (ss > 0.f) ? 1.f : 0.f;
    }
  } else if (blk < NODES / 4 + (CAT_ * 128) / 256) {
    int idx = (blk - NODES / 4) * 256 + threadIdx.x;
    int c = idx >> 7, d = idx & 127;
    int l = c >> 7, o = c & 127;
    float v = A[((size_t)l * 128 + d) * 128 + o];
    unsigned short hi = f2bf(v);
    ATh[idx] = hi;
    ATl[idx] = f2bf(v - bf2f(hi));
  } else {
    int idx = (blk - NODES / 4 - (CAT_ * 128) / 256) * 256 + threadIdx.x;
    if (idx < 384 * 128) {
      int c = idx >> 7, k = idx & 127;
      float v = Wi[(size_t)k * 384 + c];
      unsigned short hi = f2bf(v);
      WiTh[idx] = hi; WiTl[idx] = f2bf(v - bf2f(hi));
    } else {
      int i = idx - 384 * 128;
      int c = i >> 7, k = i & 127;
      float v = Wh[(size_t)k * 384 + c];
      unsigned short hi = f2bf(v);
      WhTh[i] = hi; WhTl[i] = f2bf(v - bf2f(hi));
    }
  }
}

// ---------------- pack: Gb = bf16(g), Eb = u8(e)  (once) ----------------
__global__ __launch_bounds__(256) void k_pack(const float* __restrict__ g,
                                              const int* __restrict__ e,
                                              unsigned short* __restrict__ Gb,
                                              unsigned char* __restrict__ Eb) {
  size_t i8 = ((size_t)blockIdx.x * 256 + threadIdx.x) * 8;
  float4 g0 = *(const float4*)&g[i8];
  float4 g1 = *(const float4*)&g[i8 + 4];
  int4   e0 = *(const int4*)&e[i8];
  int4   e1 = *(const int4*)&e[i8 + 4];
  ushort4 ga, gb;
  ga.x = f2bf(g0.x); ga.y = f2bf(g0.y); ga.z = f2bf(g0.z); ga.w = f2bf(g0.w);
  gb.x = f2bf(g1.x); gb.y = f2bf(g1.y); gb.z = f2bf(g1.z); gb.w = f2bf(g1.w);
  *(ushort4*)&Gb[i8]     = ga;
  *(ushort4*)&Gb[i8 + 4] = gb;
  uint2 ev;
  ev.x = (unsigned)(e0.x & 0xFF) | ((unsigned)(e0.y & 0xFF) << 8) |
         ((unsigned)(e0.z & 0xFF) << 16) | ((unsigned)(e0.w & 0xFF) << 24);
  ev.y = (unsigned)(e1.x & 0xFF) | ((unsigned)(e1.y & 0xFF) << 8) |
         ((unsigned)(e1.z & 0xFF) << 16) | ((unsigned)(e1.w & 0xFF) << 24);
  *(uint2*)&Eb[i8] = ev;
}

// ---------------- McatT[b][l][o][w] via split-precision bf16 MFMA ----------------
__global__ __launch_bounds__(256) void k_gemmT(const unsigned short* __restrict__ X,
                                               const unsigned short* __restrict__ ATh,
                                               const unsigned short* __restrict__ ATl,
                                               unsigned short* __restrict__ McatT) {
  __shared__ __align__(16) unsigned short Ah[64 * 40];
  __shared__ __align__(16) unsigned short Al[64 * 40];
  __shared__ __align__(16) unsigned short Bh[128 * 40];
  __shared__ __align__(16) unsigned short Bl2[128 * 40];
  const int tid = threadIdx.x;
  const int c0 = blockIdx.x * 128;
  const int node0 = blockIdx.y * 64;
  const int b = node0 >> 10;
  const int w0 = node0 & 1023;
  const int wid = tid >> 6, lane = tid & 63;
  const int wr = wid >> 1, wc = wid & 1;
  const int lr = lane & 15, lg = lane >> 4;
  const int ar = tid >> 2, aq = (tid & 3) * 8;
  const int br = tid >> 1, bq = (tid & 1) * 16;
  f32x4 acc[2][4];
  #pragma unroll
  for (int m = 0; m < 2; ++m)
    #pragma unroll
    for (int n = 0; n < 4; ++n) acc[m][n] = {0.f, 0.f, 0.f, 0.f};
  for (int kk = 0; kk < 4; ++kk) {
    const int kb = kk * 32;
    *(uint4*)&Ah[ar * 40 + aq] = *(const uint4*)&X[(size_t)(node0 + ar) * 256 + kb + aq];
    *(uint4*)&Al[ar * 40 + aq] = *(const uint4*)&X[(size_t)(node0 + ar) * 256 + 128 + kb + aq];
    const unsigned short* bh = ATh + (size_t)(c0 + br) * 128 + kb + bq;
    const unsigned short* bl = ATl + (size_t)(c0 + br) * 128 + kb + bq;
    *(uint4*)&Bh[br * 40 + bq]      = *(const uint4*)bh;
    *(uint4*)&Bh[br * 40 + bq + 8]  = *(const uint4*)(bh + 8);
    *(uint4*)&Bl2[br * 40 + bq]     = *(const uint4*)bl;
    *(uint4*)&Bl2[br * 40 + bq + 8] = *(const uint4*)(bl + 8);
    __syncthreads();
    s16x8 ah[2], al[2], bhf[4], blf[4];
    #pragma unroll
    for (int m = 0; m < 2; ++m) {
      int row = (wr * 32 + m * 16 + lr) * 40 + lg * 8;
      ah[m] = *(const s16x8*)&Ah[row];
      al[m] = *(const s16x8*)&Al[row];
    }
    #pragma unroll
    for (int n = 0; n < 4; ++n) {
      int row = (wc * 64 + n * 16 + lr) * 40 + lg * 8;
      bhf[n] = *(const s16x8*)&Bh[row];
      blf[n] = *(const s16x8*)&Bl2[row];
    }
    #pragma unroll
    for (int m = 0; m < 2; ++m)
      #pragma unroll
      for (int n = 0; n < 4; ++n) {
        acc[m][n] = __builtin_amdgcn_mfma_f32_16x16x32_bf16(ah[m], bhf[n], acc[m][n], 0, 0, 0);
        acc[m][n] = __builtin_amdgcn_mfma_f32_16x16x32_bf16(ah[m], blf[n], acc[m][n], 0, 0, 0);
        acc[m][n] = __builtin_amdgcn_mfma_f32_16x16x32_bf16(al[m], bhf[n], acc[m][n], 0, 0, 0);
      }
    __syncthreads();
  }
  #pragma unroll
  for (int m = 0; m < 2; ++m)
    #pragma unroll
    for (int n = 0; n < 4; ++n) {
      int c = c0 + wc * 64 + n * 16 + lr;
      int l = c >> 7, o = c & 127;
      int w = w0 + wr * 32 + m * 16 + lg * 4;
      ushort4 v;
      v.x = f2bf(acc[m][n][0]); v.y = f2bf(acc[m][n][1]);
      v.z = f2bf(acc[m][n][2]); v.w = f2bf(acc[m][n][3]);
      *(ushort4*)&McatT[(((size_t)b * L_ + l) * MSG2 + o) * N_ + w] = v;
    }
}

// ---------------- agg: barrierless LDS-free register MFMA ----------------
// Each wave owns a 32v x 32o tile; all operands are per-lane contiguous 16B
// global reads in MFMA fragment layout (lanes lr span 16 rows, lg spans the
// 64B row chunk -> fully coalesced). NO __syncthreads, NO LDS: compiler
// software-pipelines loads across k-iterations with counted waits (the
// barrier vmcnt(0) drain that pinned all prior variants at ~40us is gone).
// Cross-wave B-reuse served by L2 (XCD grouping keeps sharers on one L2).
// Same mask/bf16/MFMA order as r11/r18 => bit-identical numerics.
__global__ __launch_bounds__(256) void k_agg_reg(const unsigned short* __restrict__ Gb,
                                                 const unsigned char* __restrict__ Eb,
                                                 const unsigned short* __restrict__ McatT,
                                                 float* __restrict__ aggP) {
  const int tid = threadIdx.x;
  // XCD grouping: 32 blocks sharing (ks,b) -> same XCD.
  const int fid = blockIdx.x;          // 0..1023
  const int xcd = fid & 7;
  const int s   = fid >> 3;
  const int p   = xcd * 4 + (s >> 5);  // (ks,b) pair 0..31
  const int idx = s & 31;
  const int v0  = (idx & 15) * 64;
  const int oh  = idx >> 4;            // o-half 0/1
  const int ks  = p >> 3;
  const int b   = p & 7;

  const int wid = tid >> 6, lane = tid & 63;
  const int vw = v0 + (wid & 1) * 32;          // wave v-origin
  const int ow = oh * 64 + (wid >> 1) * 32;    // wave o-origin
  const int lr = lane & 15, lg = lane >> 4;

  f32x4 acc[2][2];
  #pragma unroll
  for (int m = 0; m < 2; ++m)
    #pragma unroll
    for (int n = 0; n < 2; ++n) acc[m][n] = {0.f, 0.f, 0.f, 0.f};

  const int kb0 = ks * 256 + lg * 8;
  // per-lane element offsets (shorts for Gb/McatT; same index = byte off for Eb)
  size_t gOff0 = ((size_t)b * N_ + vw + lr) * N_ + kb0;          // A row, m=0
  size_t gOff1 = gOff0 + (size_t)16 * N_;                        // m=1
  size_t bOff  = (((size_t)b * L_) * MSG2 + ow + lr) * N_ + kb0; // B row, l=0,n=0
  const size_t nStep = (size_t)16 * N_;
  const size_t lStep = (size_t)MSG2 * N_;

  for (int kk = 0; kk < 8; ++kk) {
    s16x8 gs0 = *(const s16x8*)(Gb + gOff0);
    s16x8 gs1 = *(const s16x8*)(Gb + gOff1);
    uint2 es0 = *(const uint2*)(Eb + gOff0);
    uint2 es1 = *(const uint2*)(Eb + gOff1);
    #pragma unroll
    for (int l = 0; l < L_; ++l) {
      s16x8 bf0 = *(const s16x8*)(McatT + bOff + (size_t)l * lStep);
      s16x8 bf1 = *(const s16x8*)(McatT + bOff + (size_t)l * lStep + nStep);
      {
        unsigned int w0e = es0.x, w1e = es0.y;
        s16x8 af;
        af[0] = (((w0e      ) & 0xFFu) == (unsigned)l) ? gs0[0] : (short)0;
        af[1] = (((w0e >>  8) & 0xFFu) == (unsigned)l) ? gs0[1] : (short)0;
        af[2] = (((w0e >> 16) & 0xFFu) == (unsigned)l) ? gs0[2] : (short)0;
        af[3] = (((w0e >> 24) & 0xFFu) == (unsigned)l) ? gs0[3] : (short)0;
        af[4] = (((w1e      ) & 0xFFu) == (unsigned)l) ? gs0[4] : (short)0;
        af[5] = (((w1e >>  8) & 0xFFu) == (unsigned)l) ? gs0[5] : (short)0;
        af[6] = (((w1e >> 16) & 0xFFu) == (unsigned)l) ? gs0[6] : (short)0;
        af[7] = (((w1e >> 24) & 0xFFu) == (unsigned)l) ? gs0[7] : (short)0;
        acc[0][0] = __builtin_amdgcn_mfma_f32_16x16x32_bf16(af, bf0, acc[0][0], 0, 0, 0);
        acc[0][1] = __builtin_amdgcn_mfma_f32_16x16x32_bf16(af, bf1, acc[0][1], 0, 0, 0);
      }
      {
        unsigned int w0e = es1.x, w1e = es1.y;
        s16x8 af;
        af[0] = (((w0e      ) & 0xFFu) == (unsigned)l) ? gs1[0] : (short)0;
        af[1] = (((w0e >>  8) & 0xFFu) == (unsigned)l) ? gs1[1] : (short)0;
        af[2] = (((w0e >> 16) & 0xFFu) == (unsigned)l) ? gs1[2] : (short)0;
        af[3] = (((w0e >> 24) & 0xFFu) == (unsigned)l) ? gs1[3] : (short)0;
        af[4] = (((w1e      ) & 0xFFu) == (unsigned)l) ? gs1[4] : (short)0;
        af[5] = (((w1e >>  8) & 0xFFu) == (unsigned)l) ? gs1[5] : (short)0;
        af[6] = (((w1e >> 16) & 0xFFu) == (unsigned)l) ? gs1[6] : (short)0;
        af[7] = (((w1e >> 24) & 0xFFu) == (unsigned)l) ? gs1[7] : (short)0;
        acc[1][0] = __builtin_amdgcn_mfma_f32_16x16x32_bf16(af, bf0, acc[1][0], 0, 0, 0);
        acc[1][1] = __builtin_amdgcn_mfma_f32_16x16x32_bf16(af, bf1, acc[1][1], 0, 0, 0);
      }
    }
    gOff0 += 32; gOff1 += 32; bOff += 32;
  }

  float* op = aggP + ((size_t)ks * NODES + (size_t)b * N_) * MSG2;
  #pragma unroll
  for (int m = 0; m < 2; ++m)
    #pragma unroll
    for (int n = 0; n < 2; ++n)
      #pragma unroll
      for (int j = 0; j < 4; ++j) {
        int row = vw + m * 16 + lg * 4 + j;
        int col = ow + n * 16 + lr;
        op[(size_t)row * MSG2 + col] = acc[m][n][j];
      }
}

// ---------------- gates via split-precision bf16 MFMA, xprep fused into z=0 A-stage ----------------
__global__ __launch_bounds__(256) void k_gates_mfma(const float* __restrict__ aggP,
                                                    const unsigned short* __restrict__ Xh,
                                                    const unsigned short* __restrict__ WiTh,
                                                    const unsigned short* __restrict__ WiTl,
                                                    const unsigned short* __restrict__ WhTh,
                                                    const unsigned short* __restrict__ WhTl,
                                                    float* __restrict__ gates) {
  __shared__ __align__(16) unsigned short Ah[64 * 40];
  __shared__ __align__(16) unsigned short Al[64 * 40];
  __shared__ __align__(16) unsigned short Bh[128 * 40];
  __shared__ __align__(16) unsigned short Bl2[128 * 40];
  const int tid = threadIdx.x;
  const int z = blockIdx.z;
  const unsigned short* WTh = z ? WhTh : WiTh;
  const unsigned short* WTl = z ? WhTl : WiTl;
  const int c0 = blockIdx.x * 128;
  const int node0 = blockIdx.y * 64;
  const int wid = tid >> 6, lane = tid & 63;
  const int wr = wid >> 1, wc = wid & 1;
  const int lr = lane & 15, lg = lane >> 4;
  const int ar = tid >> 2, aq = (tid & 3) * 8;
  const int br = tid >> 1, bq = (tid & 1) * 16;
  const size_t slab = (size_t)NODES * MSG2;
  f32x4 acc[2][4];
  #pragma unroll
  for (int m = 0; m < 2; ++m)
    #pragma unroll
    for (int n = 0; n < 4; ++n) acc[m][n] = {0.f, 0.f, 0.f, 0.f};
  for (int kk = 0; kk < 4; ++kk) {
    const int kb = kk * 32;
    if (z == 0) {
      const float* ap = aggP + (size_t)(node0 + ar) * MSG2 + kb + aq;
      float sv[8] = {0.f, 0.f, 0.f, 0.f, 0.f, 0.f, 0.f, 0.f};
      #pragma unroll
      for (int ss = 0; ss < KSPLIT; ++ss) {
        float4 x0 = *(const float4*)(ap + (size_t)ss * slab);
        float4 x1 = *(const float4*)(ap + (size_t)ss * slab + 4);
        sv[0] += x0.x; sv[1] += x0.y; sv[2] += x0.z; sv[3] += x0.w;
        sv[4] += x1.x; sv[5] += x1.y; sv[6] += x1.z; sv[7] += x1.w;
      }
      s16x8 hv, lv;
      #pragma unroll
      for (int j = 0; j < 8; ++j) {
        unsigned short hi = f2bf(sv[j]);
        hv[j] = (short)hi;
        lv[j] = (short)f2bf(sv[j] - bf2f(hi));
      }
      *(s16x8*)&Ah[ar * 40 + aq] = hv;
      *(s16x8*)&Al[ar * 40 + aq] = lv;
    } else {
      *(uint4*)&Ah[ar * 40 + aq] = *(const uint4*)&Xh[(size_t)(node0 + ar) * 256 + kb + aq];
      *(uint4*)&Al[ar * 40 + aq] = *(const uint4*)&Xh[(size_t)(node0 + ar) * 256 + 128 + kb + aq];
    }
    const unsigned short* bh = WTh + (size_t)(c0 + br) * 128 + kb + bq;
    const unsigned short* bl = WTl + (size_t)(c0 + br) * 128 + kb + bq;
    *(uint4*)&Bh[br * 40 + bq]      = *(const uint4*)bh;
    *(uint4*)&Bh[br * 40 + bq + 8]  = *(const uint4*)(bh + 8);
    *(uint4*)&Bl2[br * 40 + bq]     = *(const uint4*)bl;
    *(uint4*)&Bl2[br * 40 + bq + 8] = *(const uint4*)(bl + 8);
    __syncthreads();
    s16x8 ah[2], al[2], bhf[4], blf[4];
    #pragma unroll
    for (int m = 0; m < 2; ++m) {
      int row = (wr * 32 + m * 16 + lr) * 40 + lg * 8;
      ah[m] = *(const s16x8*)&Ah[row];
      al[m] = *(const s16x8*)&Al[row];
    }
    #pragma unroll
    for (int n = 0; n < 4; ++n) {
      int row = (wc * 64 + n * 16 + lr) * 40 + lg * 8;
      bhf[n] = *(const s16x8*)&Bh[row];
      blf[n] = *(const s16x8*)&Bl2[row];
    }
    #pragma unroll
    for (int m = 0; m < 2; ++m)
      #pragma unroll
      for (int n = 0; n < 4; ++n) {
        acc[m][n] = __builtin_amdgcn_mfma_f32_16x16x32_bf16(ah[m], bhf[n], acc[m][n], 0, 0, 0);
        acc[m][n] = __builtin_amdgcn_mfma_f32_16x16x32_bf16(ah[m], blf[n], acc[m][n], 0, 0, 0);
        acc[m][n] = __builtin_amdgcn_mfma_f32_16x16x32_bf16(al[m], bhf[n], acc[m][n], 0, 0, 0);
      }
    __syncthreads();
  }
  #pragma unroll
  for (int m = 0; m < 2; ++m)
    #pragma unroll
    for (int n = 0; n < 4; ++n) {
      int c = c0 + wc * 64 + n * 16 + lr;
      int row = node0 + wr * 32 + m * 16 + lg * 4;
      #pragma unroll
      for (int j = 0; j < 4; ++j)
        gates[(size_t)(row + j) * 768 + z * 384 + c] = acc[m][n][j];
    }
}

// ---------------- GRU elementwise (+ optional X hi/lo write) ----------------
__global__ __launch_bounds__(256) void k_gru_elt(const float* __restrict__ gates,
                                                 const float* __restrict__ bi,
                                                 const float* __restrict__ bh,
                                                 const float* __restrict__ maskA,
                                                 float* __restrict__ h,
                                                 unsigned short* __restrict__ X,
                                                 int writeX) {
  const int t = threadIdx.x;
  const int node = blockIdx.x * 8 + (t >> 5);
  const int j4 = (t & 31) * 4;
  const size_t gb = (size_t)node * 768;
  float4 gir = *(const float4*)&gates[gb + j4];
  float4 giz = *(const float4*)&gates[gb + 128 + j4];
  float4 gin = *(const float4*)&gates[gb + 256 + j4];
  float4 ghr = *(const float4*)&gates[gb + 384 + j4];
  float4 ghz = *(const float4*)&gates[gb + 512 + j4];
  float4 ghn = *(const float4*)&gates[gb + 640 + j4];
  float4 bir = *(const float4*)&bi[j4];
  float4 biz = *(const float4*)&bi[128 + j4];
  float4 bin = *(const float4*)&bi[256 + j4];
  float4 bhr = *(const float4*)&bh[j4];
  float4 bhz = *(const float4*)&bh[128 + j4];
  float4 bhn = *(const float4*)&bh[256 + j4];
  float4 hv = *(const float4*)&h[(size_t)node * 128 + j4];
  float m = maskA[node];
  float4 ho;
  {
    float r = sigmoidf_(gir.x + bir.x + ghr.x + bhr.x);
    float z = sigmoidf_(giz.x + biz.x + ghz.x + bhz.x);
    float nn = tanhf(gin.x + bin.x + r * (ghn.x + bhn.x));
    ho.x = ((1.f - z) * nn + z * hv.x) * m;
  }
  {
    float r = sigmoidf_(gir.y + bir.y + ghr.y + bhr.y);
    float z = sigmoidf_(giz.y + biz.y + ghz.y + bhz.y);
    float nn = tanhf(gin.y + bin.y + r * (ghn.y + bhn.y));
    ho.y = ((1.f - z) * nn + z * hv.y) * m;
  }
  {
    float r = sigmoidf_(gir.z + bir.z + ghr.z + bhr.z);
    float z = sigmoidf_(giz.z + biz.z + ghz.z + bhz.z);
    float nn = tanhf(gin.z + bin.z + r * (ghn.z + bhn.z));
    ho.z = ((1.f - z) * nn + z * hv.z) * m;
  }
  {
    float r = sigmoidf_(gir.w + bir.w + ghr.w + bhr.w);
    float z = sigmoidf_(giz.w + biz.w + ghz.w + bhz.w);
    float nn = tanhf(gin.w + bin.w + r * (ghn.w + bhn.w));
    ho.w = ((1.f - z) * nn + z * hv.w) * m;
  }
  *(float4*)&h[(size_t)node * 128 + j4] = ho;
  if (writeX) {
    ushort4 hi, lo;
    hi.x = f2bf(ho.x); lo.x = f2bf(ho.x - bf2f(hi.x));
    hi.y = f2bf(ho.y); lo.y = f2bf(ho.y - bf2f(hi.y));
    hi.z = f2bf(ho.z); lo.z = f2bf(ho.z - bf2f(hi.z));
    hi.w = f2bf(ho.w); lo.w = f2bf(ho.w - bf2f(hi.w));
    *(ushort4*)&X[(size_t)node * 256 + j4]       = hi;
    *(ushort4*)&X[(size_t)node * 256 + 128 + j4] = lo;
  }
}

// ---------------- readout stage 1: PT[c][node] = ([hT,h0] @ Wcat)[node][c] ----------------
__global__ __launch_bounds__(256) void k_readP(const float* __restrict__ h,
                                               const float* __restrict__ h0,
                                               const float* __restrict__ Wg,
                                               const float* __restrict__ Wo,
                                               float* __restrict__ PT) {
  __shared__ float Xt[64][65];
  __shared__ float Wt[64][25];
  const int tid = threadIdx.x;
  const int node0 = blockIdx.x * 64;
  const int row = tid >> 2;
  const int cg  = tid & 3;
  float acc[6] = {0.f, 0.f, 0.f, 0.f, 0.f, 0.f};
  const int sr = tid >> 2;
  const int sk = (tid & 3) * 16;
  #pragma unroll
  for (int kb = 0; kb < 4; ++kb) {
    const float* src = (kb < 2 ? h : h0) + (size_t)(node0 + sr) * 128 + (kb & 1) * 64 + sk;
    #pragma unroll
    for (int q = 0; q < 4; ++q)
      *(float4*)&Xt[sr][sk + q * 4] = *(const float4*)(src + q * 4);
    #pragma unroll
    for (int j = 0; j < 6; ++j) {
      int idx = tid * 6 + j;
      int rk = idx / 24;
      int c24 = idx - rk * 24;
      int gk = kb * 64 + rk;
      float wv;
      if (c24 < 12) wv = Wg[(size_t)gk * TGT_ + c24];
      else          wv = (gk < 128) ? Wo[(size_t)gk * TGT_ + (c24 - 12)] : 0.f;
      Wt[rk][c24] = wv;
    }
    __syncthreads();
    #pragma unroll 8
    for (int k = 0; k < 64; ++k) {
      float x = Xt[row][k];
      #pragma unroll
      for (int j = 0; j < 6; ++j)
        acc[j] += x * Wt[k][cg * 6 + j];
    }
    __syncthreads();
  }
  #pragma unroll
  for (int j = 0; j < 6; ++j)
    PT[(size_t)(cg * 6 + j) * NODES + node0 + row] = acc[j];
}

// ---------------- readout stage 2 ----------------
__global__ __launch_bounds__(256) void k_readR(const float* __restrict__ PT,
                                               const float* __restrict__ maskR,
                                               const float* __restrict__ bg,
                                               const float* __restrict__ bo,
                                               float* __restrict__ out) {
  __shared__ float red[256];
  const int tid = threadIdx.x;
  const int b = blockIdx.x / TGT_;
  const int t = blockIdx.x - b * TGT_;
  const float bgt = bg[t], bot = bo[t];
  float s = 0.f;
  #pragma unroll
  for (int i = 0; i < 4; ++i) {
    int node = b * N_ + i * 256 + tid;
    float p1 = PT[(size_t)t * NODES + node] + bgt;
    float p2 = PT[(size_t)(12 + t) * NODES + node] + bot;
    s += sigmoidf_(p1) * p2 * maskR[node];
  }
  red[tid] = s;
  __syncthreads();
  #pragma unroll
  for (int off = 128; off > 0; off >>= 1) {
    if (tid < off) red[tid] += red[tid + off];
    __syncthreads();
  }
  if (tid == 0) out[b * TGT_ + t] = red[0];
}

extern "C" void kernel_launch(void* const* d_in, const int* in_sizes, int n_in,
                              void* d_out, int out_size, void* d_ws, size_t ws_size,
                              hipStream_t stream) {
  (void)in_sizes; (void)n_in; (void)out_size; (void)ws_size;
  const float* g    = (const float*)d_in[0];
  const float* h_in = (const float*)d_in[1];
  const int*   e    = (const int*)d_in[2];
  const float* A    = (const float*)d_in[3];
  const float* Wi   = (const float*)d_in[4];
  const float* Wh   = (const float*)d_in[5];
  const float* bi   = (const float*)d_in[6];
  const float* bh   = (const float*)d_in[7];
  const float* Wg   = (const float*)d_in[8];
  const float* bg   = (const float*)d_in[9];
  const float* Wo   = (const float*)d_in[10];
  const float* bo   = (const float*)d_in[11];
  float* out = (float*)d_out;
  float* ws  = (float*)d_ws;

  // workspace layout (~92 MB):
  float* h     = ws;                                   // 1,048,576 f
  float* h0    = h + (size_t)NODES * H_;               // 1,048,576 f
  float* maskA = h0 + (size_t)NODES * H_;              // 8192 f
  float* maskR = maskA + NODES;                        // 8192 f
  float* PT    = maskR + NODES;                        // 196,608 f (readout scratch)
  unsigned short* X    = (unsigned short*)(PT + 24 * NODES);  // 2,097,152 us (h hi|lo)
  unsigned short* ATh  = X + (size_t)NODES * 256;      // 81,920 us
  unsigned short* ATl  = ATh + CAT_ * 128;             // 81,920 us
  unsigned short* WiTh = ATl + CAT_ * 128;             // 49,152 us
  unsigned short* WiTl = WiTh + 384 * 128;             // 49,152 us
  unsigned short* WhTh = WiTl + 384 * 128;             // 49,152 us
  unsigned short* WhTl = WhTh + 384 * 128;             // 49,152 us
  unsigned short* Gb   = WhTl + 384 * 128;             // 8,388,608 us (16.8 MB)
  unsigned char*  Eb   = (unsigned char*)(Gb + (size_t)NODES * N_);   // 8,388,608 u8
  float* aggP = (float*)(Eb + (size_t)NODES * N_);     // KSPLIT * 1,048,576 f (16.8 MB)
  unsigned short* McatT = (unsigned short*)(aggP + (size_t)KSPLIT * NODES * MSG2); // 10.5 MB
  float* gates = (float*)(McatT + (size_t)B_ * L_ * MSG2 * N_);       // 6,291,456 f (25.2 MB)

  k_prep<<<NODES / 4 + (CAT_ * 128) / 256 + (2 * 384 * 128) / 256, 256, 0, stream>>>(
      h_in, A, Wi, Wh, h, h0, X, maskA, maskR, ATh, ATl, WiTh, WiTl, WhTh, WhTl);
  k_pack<<<(NODES * N_ / 8) / 256, 256, 0, stream>>>(g, e, Gb, Eb);
  for (int layer = 0; layer < NLAYERS_; ++layer) {
    k_gemmT<<<dim3(CAT_ / 128, NODES / 64), 256, 0, stream>>>(X, ATh, ATl, McatT);
    k_agg_reg<<<(N_ / 64) * 2 * KSPLIT * B_, 256, 0, stream>>>(Gb, Eb, McatT, aggP);
    k_gates_mfma<<<dim3(384 / 128, NODES / 64, 2), 256, 0, stream>>>(aggP, X, WiTh, WiTl, WhTh, WhTl, gates);
    k_gru_elt<<<NODES / 8, 256, 0, stream>>>(gates, bi, bh, maskA, h, X,
                                             (layer < NLAYERS_ - 1) ? 1 : 0);
  }
  k_readP<<<NODES / 64, 256, 0, stream>>>(h, h0, Wg, Wo, PT);
  k_readR<<<B_ * TGT_, 256, 0, stream>>>(PT, maskR, bg, bo, out);
}

// Round 20
// 219.507 us; speedup vs baseline: 1.3963x; 1.3963x over previous
//
#include <hip/hip_runtime.h>

#define B_      8
#define N_      1024
#define DIN_    64
#define H_      128
#define MSG2    128
#define L_      5
#define TGT_    12
#define NLAYERS_ 3
#define CAT_    640          // L_ * MSG2
#define NODES   (B_ * N_)    // 8192
#define KSPLIT  4

typedef __attribute__((ext_vector_type(8))) short s16x8;
typedef __attribute__((ext_vector_type(4))) float f32x4;

__device__ __forceinline__ float sigmoidf_(float x) { return 1.f / (1.f + __expf(-x)); }

__device__ __forceinline__ unsigned short f2bf(float x) {
  unsigned int u = __float_as_uint(x);
  u += 0x7FFFu + ((u >> 16) & 1u);      // round-to-nearest-even
  return (unsigned short)(u >> 16);
}
__device__ __forceinline__ float bf2f(unsigned short u) {
  return __uint_as_float(((unsigned int)u) << 16);
}

// ---------------- merged prep: init | aprep | wprep ----------------
__global__ __launch_bounds__(256) void k_prep(const float* __restrict__ h_in,
                                              const float* __restrict__ A,
                                              const float* __restrict__ Wi,
                                              const float* __restrict__ Wh,
                                              float* __restrict__ h,
                                              float* __restrict__ h0,
                                              unsigned short* __restrict__ X,
                                              float* __restrict__ maskA,
                                              float* __restrict__ maskR,
                                              unsigned short* __restrict__ ATh,
                                              unsigned short* __restrict__ ATl,
                                              unsigned short* __restrict__ WiTh,
                                              unsigned short* __restrict__ WiTl,
                                              unsigned short* __restrict__ WhTh,
                                              unsigned short* __restrict__ WhTl) {
  const int blk = blockIdx.x;
  if (blk < NODES / 4) {
    int node = blk * 4 + (threadIdx.x >> 6);
    int lane = threadIdx.x & 63;
    float v = h_in[(size_t)node * DIN_ + lane];
    size_t base = (size_t)node * H_;
    h[base + lane] = v;   h[base + 64 + lane] = 0.f;
    h0[base + lane] = v;  h0[base + 64 + lane] = 0.f;
    unsigned short hi = f2bf(v);
    unsigned short lo = f2bf(v - bf2f(hi));
    size_t xb = (size_t)node * 256;
    X[xb + lane] = hi;        X[xb + 64 + lane] = 0;
    X[xb + 128 + lane] = lo;  X[xb + 192 + lane] = 0;
    float sa = fabsf(v), ss = v;
    for (int off = 32; off > 0; off >>= 1) {
      sa += __shfl_down(sa, off);
      ss += __shfl_down(ss, off);
    }
    if (lane == 0) {
      maskA[node] = (sa > 0.f) ? 1.f : 0.f;
      maskR[node] = (ss > 0.f) ? 1.f : 0.f;
    }
  } else if (blk < NODES / 4 + (CAT_ * 128) / 256) {
    int idx = (blk - NODES / 4) * 256 + threadIdx.x;
    int c = idx >> 7, d = idx & 127;
    int l = c >> 7, o = c & 127;
    float v = A[((size_t)l * 128 + d) * 128 + o];
    unsigned short hi = f2bf(v);
    ATh[idx] = hi;
    ATl[idx] = f2bf(v - bf2f(hi));
  } else {
    int idx = (blk - NODES / 4 - (CAT_ * 128) / 256) * 256 + threadIdx.x;
    if (idx < 384 * 128) {
      int c = idx >> 7, k = idx & 127;
      float v = Wi[(size_t)k * 384 + c];
      unsigned short hi = f2bf(v);
      WiTh[idx] = hi; WiTl[idx] = f2bf(v - bf2f(hi));
    } else {
      int i = idx - 384 * 128;
      int c = i >> 7, k = i & 127;
      float v = Wh[(size_t)k * 384 + c];
      unsigned short hi = f2bf(v);
      WhTh[i] = hi; WhTl[i] = f2bf(v - bf2f(hi));
    }
  }
}

// ---------------- pack: Gb = bf16(g), Eb = u8(e)  (once) ----------------
__global__ __launch_bounds__(256) void k_pack(const float* __restrict__ g,
                                              const int* __restrict__ e,
                                              unsigned short* __restrict__ Gb,
                                              unsigned char* __restrict__ Eb) {
  size_t i8 = ((size_t)blockIdx.x * 256 + threadIdx.x) * 8;
  float4 g0 = *(const float4*)&g[i8];
  float4 g1 = *(const float4*)&g[i8 + 4];
  int4   e0 = *(const int4*)&e[i8];
  int4   e1 = *(const int4*)&e[i8 + 4];
  ushort4 ga, gb;
  ga.x = f2bf(g0.x); ga.y = f2bf(g0.y); ga.z = f2bf(g0.z); ga.w = f2bf(g0.w);
  gb.x = f2bf(g1.x); gb.y = f2bf(g1.y); gb.z = f2bf(g1.z); gb.w = f2bf(g1.w);
  *(ushort4*)&Gb[i8]     = ga;
  *(ushort4*)&Gb[i8 + 4] = gb;
  uint2 ev;
  ev.x = (unsigned)(e0.x & 0xFF) | ((unsigned)(e0.y & 0xFF) << 8) |
         ((unsigned)(e0.z & 0xFF) << 16) | ((unsigned)(e0.w & 0xFF) << 24);
  ev.y = (unsigned)(e1.x & 0xFF) | ((unsigned)(e1.y & 0xFF) << 8) |
         ((unsigned)(e1.z & 0xFF) << 16) | ((unsigned)(e1.w & 0xFF) << 24);
  *(uint2*)&Eb[i8] = ev;
}

// ---------------- McatT[b][l][o][w] via split-precision bf16 MFMA ----------------
__global__ __launch_bounds__(256) void k_gemmT(const unsigned short* __restrict__ X,
                                               const unsigned short* __restrict__ ATh,
                                               const unsigned short* __restrict__ ATl,
                                               unsigned short* __restrict__ McatT) {
  __shared__ __align__(16) unsigned short Ah[64 * 40];
  __shared__ __align__(16) unsigned short Al[64 * 40];
  __shared__ __align__(16) unsigned short Bh[128 * 40];
  __shared__ __align__(16) unsigned short Bl2[128 * 40];
  const int tid = threadIdx.x;
  const int c0 = blockIdx.x * 128;
  const int node0 = blockIdx.y * 64;
  const int b = node0 >> 10;
  const int w0 = node0 & 1023;
  const int wid = tid >> 6, lane = tid & 63;
  const int wr = wid >> 1, wc = wid & 1;
  const int lr = lane & 15, lg = lane >> 4;
  const int ar = tid >> 2, aq = (tid & 3) * 8;
  const int br = tid >> 1, bq = (tid & 1) * 16;
  f32x4 acc[2][4];
  #pragma unroll
  for (int m = 0; m < 2; ++m)
    #pragma unroll
    for (int n = 0; n < 4; ++n) acc[m][n] = {0.f, 0.f, 0.f, 0.f};
  for (int kk = 0; kk < 4; ++kk) {
    const int kb = kk * 32;
    *(uint4*)&Ah[ar * 40 + aq] = *(const uint4*)&X[(size_t)(node0 + ar) * 256 + kb + aq];
    *(uint4*)&Al[ar * 40 + aq] = *(const uint4*)&X[(size_t)(node0 + ar) * 256 + 128 + kb + aq];
    const unsigned short* bh = ATh + (size_t)(c0 + br) * 128 + kb + bq;
    const unsigned short* bl = ATl + (size_t)(c0 + br) * 128 + kb + bq;
    *(uint4*)&Bh[br * 40 + bq]      = *(const uint4*)bh;
    *(uint4*)&Bh[br * 40 + bq + 8]  = *(const uint4*)(bh + 8);
    *(uint4*)&Bl2[br * 40 + bq]     = *(const uint4*)bl;
    *(uint4*)&Bl2[br * 40 + bq + 8] = *(const uint4*)(bl + 8);
    __syncthreads();
    s16x8 ah[2], al[2], bhf[4], blf[4];
    #pragma unroll
    for (int m = 0; m < 2; ++m) {
      int row = (wr * 32 + m * 16 + lr) * 40 + lg * 8;
      ah[m] = *(const s16x8*)&Ah[row];
      al[m] = *(const s16x8*)&Al[row];
    }
    #pragma unroll
    for (int n = 0; n < 4; ++n) {
      int row = (wc * 64 + n * 16 + lr) * 40 + lg * 8;
      bhf[n] = *(const s16x8*)&Bh[row];
      blf[n] = *(const s16x8*)&Bl2[row];
    }
    #pragma unroll
    for (int m = 0; m < 2; ++m)
      #pragma unroll
      for (int n = 0; n < 4; ++n) {
        acc[m][n] = __builtin_amdgcn_mfma_f32_16x16x32_bf16(ah[m], bhf[n], acc[m][n], 0, 0, 0);
        acc[m][n] = __builtin_amdgcn_mfma_f32_16x16x32_bf16(ah[m], blf[n], acc[m][n], 0, 0, 0);
        acc[m][n] = __builtin_amdgcn_mfma_f32_16x16x32_bf16(al[m], bhf[n], acc[m][n], 0, 0, 0);
      }
    __syncthreads();
  }
  #pragma unroll
  for (int m = 0; m < 2; ++m)
    #pragma unroll
    for (int n = 0; n < 4; ++n) {
      int c = c0 + wc * 64 + n * 16 + lr;
      int l = c >> 7, o = c & 127;
      int w = w0 + wr * 32 + m * 16 + lg * 4;
      ushort4 v;
      v.x = f2bf(acc[m][n][0]); v.y = f2bf(acc[m][n][1]);
      v.z = f2bf(acc[m][n][2]); v.w = f2bf(acc[m][n][3]);
      *(ushort4*)&McatT[(((size_t)b * L_ + l) * MSG2 + o) * N_ + w] = v;
    }
}

// ---------------- agg via 5 per-label bf16 MFMA GEMMs, staging-side masking ----------------
// 64v x 64o tile, KSPLIT=4, grid 1024 (4 blocks/CU, LDS 40KB), XOR swizzle,
// XCD grouping. ~40us = this problem-shape's floor (10 structural variants
// r8-r19 all 40+-5us: occupancy/pipelining/mask-placement/barriers eliminated).
__global__ __launch_bounds__(256, 4) void k_agg_mfma(const unsigned short* __restrict__ Gb,
                                                     const unsigned char* __restrict__ Eb,
                                                     const unsigned short* __restrict__ McatT,
                                                     float* __restrict__ aggP) {
  __shared__ __align__(16) unsigned short Gm[L_][64 * 32];  // 20 KB, pre-masked, swizzled
  __shared__ __align__(16) unsigned short Bl[L_][64 * 32];  // 20 KB, swizzled
  char* GmB = (char*)Gm;   // label stride 4096 B
  char* BlB = (char*)Bl;

  const int tid = threadIdx.x;
  const int fid = blockIdx.x;          // 0..1023
  const int xcd = fid & 7;
  const int s   = fid >> 3;
  const int p   = xcd * 4 + (s >> 5);  // (ks,b) pair 0..31
  const int idx = s & 31;
  const int v0  = (idx & 15) * 64;
  const int oh  = idx >> 4;
  const int ks  = p >> 3;
  const int b   = p & 7;

  const int wid  = tid >> 6, lane = tid & 63;
  const int wr   = wid >> 1, wc = wid & 1;    // wave tile 32v x 32o
  const int lr   = lane & 15, lg = lane >> 4;

  f32x4 acc[2][2];
  #pragma unroll
  for (int m = 0; m < 2; ++m)
    #pragma unroll
    for (int n = 0; n < 2; ++n) acc[m][n] = {0.f, 0.f, 0.f, 0.f};

  const int ar = tid >> 2, aq = (tid & 3) * 8;
  const int br = tid >> 2, bq = (tid & 3) * 8;
  const size_t garow = ((size_t)b * N_ + v0 + ar) * N_;
  const size_t mrowb = (((size_t)b * L_) * MSG2 + oh * 64 + br) * N_;
  const size_t lstep = (size_t)MSG2 * N_;
  const int ksbase = ks * 256;

  const int gt_w = (ar * 64 + aq * 2) ^ ((ar & 7) << 4);
  const int bl_w = (br * 64 + bq * 2) ^ ((br & 7) << 4);
  const int fsw  = (lr & 7) << 4;

  for (int kk = 0; kk < 8; ++kk) {
    const int kb = ksbase + kk * 32;
    s16x8 gs = *(const s16x8*)&Gb[garow + kb + aq];
    uint2 ev = *(const uint2*)&Eb[garow + kb + aq];
    uint4 bv[L_];
    #pragma unroll
    for (int l = 0; l < L_; ++l)
      bv[l] = *(const uint4*)(McatT + mrowb + (size_t)l * lstep + kb + bq);
    {
      unsigned int w0e = ev.x, w1e = ev.y;
      #pragma unroll
      for (int l = 0; l < L_; ++l) {
        s16x8 mg;
        mg[0] = (((w0e      ) & 0xFFu) == (unsigned)l) ? gs[0] : (short)0;
        mg[1] = (((w0e >>  8) & 0xFFu) == (unsigned)l) ? gs[1] : (short)0;
        mg[2] = (((w0e >> 16) & 0xFFu) == (unsigned)l) ? gs[2] : (short)0;
        mg[3] = (((w0e >> 24) & 0xFFu) == (unsigned)l) ? gs[3] : (short)0;
        mg[4] = (((w1e      ) & 0xFFu) == (unsigned)l) ? gs[4] : (short)0;
        mg[5] = (((w1e >>  8) & 0xFFu) == (unsigned)l) ? gs[5] : (short)0;
        mg[6] = (((w1e >> 16) & 0xFFu) == (unsigned)l) ? gs[6] : (short)0;
        mg[7] = (((w1e >> 24) & 0xFFu) == (unsigned)l) ? gs[7] : (short)0;
        *(s16x8*)(GmB + l * 4096 + gt_w) = mg;
      }
    }
    #pragma unroll
    for (int l = 0; l < L_; ++l)
      *(uint4*)(BlB + l * (64 * 64) + bl_w) = bv[l];
    __syncthreads();

    #pragma unroll
    for (int l = 0; l < L_; ++l) {
      s16x8 af[2], bfr[2];
      #pragma unroll
      for (int m = 0; m < 2; ++m) {
        int row = wr * 32 + m * 16 + lr;
        af[m] = *(const s16x8*)(GmB + l * 4096 + ((row * 64 + lg * 16) ^ fsw));
      }
      #pragma unroll
      for (int n = 0; n < 2; ++n) {
        int row = wc * 32 + n * 16 + lr;
        bfr[n] = *(const s16x8*)(BlB + l * (64 * 64) + ((row * 64 + lg * 16) ^ fsw));
      }
      #pragma unroll
      for (int m = 0; m < 2; ++m)
        #pragma unroll
        for (int n = 0; n < 2; ++n)
          acc[m][n] = __builtin_amdgcn_mfma_f32_16x16x32_bf16(af[m], bfr[n], acc[m][n], 0, 0, 0);
    }
    __syncthreads();
  }

  float* op = aggP + ((size_t)ks * NODES + (size_t)b * N_ + v0) * MSG2 + oh * 64;
  #pragma unroll
  for (int m = 0; m < 2; ++m)
    #pragma unroll
    for (int n = 0; n < 2; ++n)
      #pragma unroll
      for (int j = 0; j < 4; ++j) {
        int row = wr * 32 + m * 16 + lg * 4 + j;
        int col = wc * 32 + n * 16 + lr;
        op[(size_t)row * MSG2 + col] = acc[m][n][j];
      }
}

// ---------------- gates via split-precision bf16 MFMA, xprep fused into z=0 A-stage ----------------
__global__ __launch_bounds__(256) void k_gates_mfma(const float* __restrict__ aggP,
                                                    const unsigned short* __restrict__ Xh,
                                                    const unsigned short* __restrict__ WiTh,
                                                    const unsigned short* __restrict__ WiTl,
                                                    const unsigned short* __restrict__ WhTh,
                                                    const unsigned short* __restrict__ WhTl,
                                                    float* __restrict__ gates) {
  __shared__ __align__(16) unsigned short Ah[64 * 40];
  __shared__ __align__(16) unsigned short Al[64 * 40];
  __shared__ __align__(16) unsigned short Bh[128 * 40];
  __shared__ __align__(16) unsigned short Bl2[128 * 40];
  const int tid = threadIdx.x;
  const int z = blockIdx.z;
  const unsigned short* WTh = z ? WhTh : WiTh;
  const unsigned short* WTl = z ? WhTl : WiTl;
  const int c0 = blockIdx.x * 128;
  const int node0 = blockIdx.y * 64;
  const int wid = tid >> 6, lane = tid & 63;
  const int wr = wid >> 1, wc = wid & 1;
  const int lr = lane & 15, lg = lane >> 4;
  const int ar = tid >> 2, aq = (tid & 3) * 8;
  const int br = tid >> 1, bq = (tid & 1) * 16;
  const size_t slab = (size_t)NODES * MSG2;
  f32x4 acc[2][4];
  #pragma unroll
  for (int m = 0; m < 2; ++m)
    #pragma unroll
    for (int n = 0; n < 4; ++n) acc[m][n] = {0.f, 0.f, 0.f, 0.f};
  for (int kk = 0; kk < 4; ++kk) {
    const int kb = kk * 32;
    if (z == 0) {
      const float* ap = aggP + (size_t)(node0 + ar) * MSG2 + kb + aq;
      float sv[8] = {0.f, 0.f, 0.f, 0.f, 0.f, 0.f, 0.f, 0.f};
      #pragma unroll
      for (int ss = 0; ss < KSPLIT; ++ss) {
        float4 x0 = *(const float4*)(ap + (size_t)ss * slab);
        float4 x1 = *(const float4*)(ap + (size_t)ss * slab + 4);
        sv[0] += x0.x; sv[1] += x0.y; sv[2] += x0.z; sv[3] += x0.w;
        sv[4] += x1.x; sv[5] += x1.y; sv[6] += x1.z; sv[7] += x1.w;
      }
      s16x8 hv, lv;
      #pragma unroll
      for (int j = 0; j < 8; ++j) {
        unsigned short hi = f2bf(sv[j]);
        hv[j] = (short)hi;
        lv[j] = (short)f2bf(sv[j] - bf2f(hi));
      }
      *(s16x8*)&Ah[ar * 40 + aq] = hv;
      *(s16x8*)&Al[ar * 40 + aq] = lv;
    } else {
      *(uint4*)&Ah[ar * 40 + aq] = *(const uint4*)&Xh[(size_t)(node0 + ar) * 256 + kb + aq];
      *(uint4*)&Al[ar * 40 + aq] = *(const uint4*)&Xh[(size_t)(node0 + ar) * 256 + 128 + kb + aq];
    }
    const unsigned short* bh = WTh + (size_t)(c0 + br) * 128 + kb + bq;
    const unsigned short* bl = WTl + (size_t)(c0 + br) * 128 + kb + bq;
    *(uint4*)&Bh[br * 40 + bq]      = *(const uint4*)bh;
    *(uint4*)&Bh[br * 40 + bq + 8]  = *(const uint4*)(bh + 8);
    *(uint4*)&Bl2[br * 40 + bq]     = *(const uint4*)bl;
    *(uint4*)&Bl2[br * 40 + bq + 8] = *(const uint4*)(bl + 8);
    __syncthreads();
    s16x8 ah[2], al[2], bhf[4], blf[4];
    #pragma unroll
    for (int m = 0; m < 2; ++m) {
      int row = (wr * 32 + m * 16 + lr) * 40 + lg * 8;
      ah[m] = *(const s16x8*)&Ah[row];
      al[m] = *(const s16x8*)&Al[row];
    }
    #pragma unroll
    for (int n = 0; n < 4; ++n) {
      int row = (wc * 64 + n * 16 + lr) * 40 + lg * 8;
      bhf[n] = *(const s16x8*)&Bh[row];
      blf[n] = *(const s16x8*)&Bl2[row];
    }
    #pragma unroll
    for (int m = 0; m < 2; ++m)
      #pragma unroll
      for (int n = 0; n < 4; ++n) {
        acc[m][n] = __builtin_amdgcn_mfma_f32_16x16x32_bf16(ah[m], bhf[n], acc[m][n], 0, 0, 0);
        acc[m][n] = __builtin_amdgcn_mfma_f32_16x16x32_bf16(ah[m], blf[n], acc[m][n], 0, 0, 0);
        acc[m][n] = __builtin_amdgcn_mfma_f32_16x16x32_bf16(al[m], bhf[n], acc[m][n], 0, 0, 0);
      }
    __syncthreads();
  }
  #pragma unroll
  for (int m = 0; m < 2; ++m)
    #pragma unroll
    for (int n = 0; n < 4; ++n) {
      int c = c0 + wc * 64 + n * 16 + lr;
      int row = node0 + wr * 32 + m * 16 + lg * 4;
      #pragma unroll
      for (int j = 0; j < 4; ++j)
        gates[(size_t)(row + j) * 768 + z * 384 + c] = acc[m][n][j];
    }
}

// ---------------- GRU elementwise (+ optional X hi/lo write) ----------------
__global__ __launch_bounds__(256) void k_gru_elt(const float* __restrict__ gates,
                                                 const float* __restrict__ bi,
                                                 const float* __restrict__ bh,
                                                 const float* __restrict__ maskA,
                                                 float* __restrict__ h,
                                                 unsigned short* __restrict__ X,
                                                 int writeX) {
  const int t = threadIdx.x;
  const int node = blockIdx.x * 8 + (t >> 5);
  const int j4 = (t & 31) * 4;
  const size_t gb = (size_t)node * 768;
  float4 gir = *(const float4*)&gates[gb + j4];
  float4 giz = *(const float4*)&gates[gb + 128 + j4];
  float4 gin = *(const float4*)&gates[gb + 256 + j4];
  float4 ghr = *(const float4*)&gates[gb + 384 + j4];
  float4 ghz = *(const float4*)&gates[gb + 512 + j4];
  float4 ghn = *(const float4*)&gates[gb + 640 + j4];
  float4 bir = *(const float4*)&bi[j4];
  float4 biz = *(const float4*)&bi[128 + j4];
  float4 bin = *(const float4*)&bi[256 + j4];
  float4 bhr = *(const float4*)&bh[j4];
  float4 bhz = *(const float4*)&bh[128 + j4];
  float4 bhn = *(const float4*)&bh[256 + j4];
  float4 hv = *(const float4*)&h[(size_t)node * 128 + j4];
  float m = maskA[node];
  float4 ho;
  {
    float r = sigmoidf_(gir.x + bir.x + ghr.x + bhr.x);
    float z = sigmoidf_(giz.x + biz.x + ghz.x + bhz.x);
    float nn = tanhf(gin.x + bin.x + r * (ghn.x + bhn.x));
    ho.x = ((1.f - z) * nn + z * hv.x) * m;
  }
  {
    float r = sigmoidf_(gir.y + bir.y + ghr.y + bhr.y);
    float z = sigmoidf_(giz.y + biz.y + ghz.y + bhz.y);
    float nn = tanhf(gin.y + bin.y + r * (ghn.y + bhn.y));
    ho.y = ((1.f - z) * nn + z * hv.y) * m;
  }
  {
    float r = sigmoidf_(gir.z + bir.z + ghr.z + bhr.z);
    float z = sigmoidf_(giz.z + biz.z + ghz.z + bhz.z);
    float nn = tanhf(gin.z + bin.z + r * (ghn.z + bhn.z));
    ho.z = ((1.f - z) * nn + z * hv.z) * m;
  }
  {
    float r = sigmoidf_(gir.w + bir.w + ghr.w + bhr.w);
    float z = sigmoidf_(giz.w + biz.w + ghz.w + bhz.w);
    float nn = tanhf(gin.w + bin.w + r * (ghn.w + bhn.w));
    ho.w = ((1.f - z) * nn + z * hv.w) * m;
  }
  *(float4*)&h[(size_t)node * 128 + j4] = ho;
  if (writeX) {
    ushort4 hi, lo;
    hi.x = f2bf(ho.x); lo.x = f2bf(ho.x - bf2f(hi.x));
    hi.y = f2bf(ho.y); lo.y = f2bf(ho.y - bf2f(hi.y));
    hi.z = f2bf(ho.z); lo.z = f2bf(ho.z - bf2f(hi.z));
    hi.w = f2bf(ho.w); lo.w = f2bf(ho.w - bf2f(hi.w));
    *(ushort4*)&X[(size_t)node * 256 + j4]       = hi;
    *(ushort4*)&X[(size_t)node * 256 + 128 + j4] = lo;
  }
}

// ---------------- readout stage 1: PT[c][node] = ([hT,h0] @ Wcat)[node][c] ----------------
__global__ __launch_bounds__(256) void k_readP(const float* __restrict__ h,
                                               const float* __restrict__ h0,
                                               const float* __restrict__ Wg,
                                               const float* __restrict__ Wo,
                                               float* __restrict__ PT) {
  __shared__ float Xt[64][65];
  __shared__ float Wt[64][25];
  const int tid = threadIdx.x;
  const int node0 = blockIdx.x * 64;
  const int row = tid >> 2;
  const int cg  = tid & 3;
  float acc[6] = {0.f, 0.f, 0.f, 0.f, 0.f, 0.f};
  const int sr = tid >> 2;
  const int sk = (tid & 3) * 16;
  #pragma unroll
  for (int kb = 0; kb < 4; ++kb) {
    const float* src = (kb < 2 ? h : h0) + (size_t)(node0 + sr) * 128 + (kb & 1) * 64 + sk;
    #pragma unroll
    for (int q = 0; q < 4; ++q)
      *(float4*)&Xt[sr][sk + q * 4] = *(const float4*)(src + q * 4);
    #pragma unroll
    for (int j = 0; j < 6; ++j) {
      int idx = tid * 6 + j;
      int rk = idx / 24;
      int c24 = idx - rk * 24;
      int gk = kb * 64 + rk;
      float wv;
      if (c24 < 12) wv = Wg[(size_t)gk * TGT_ + c24];
      else          wv = (gk < 128) ? Wo[(size_t)gk * TGT_ + (c24 - 12)] : 0.f;
      Wt[rk][c24] = wv;
    }
    __syncthreads();
    #pragma unroll 8
    for (int k = 0; k < 64; ++k) {
      float x = Xt[row][k];
      #pragma unroll
      for (int j = 0; j < 6; ++j)
        acc[j] += x * Wt[k][cg * 6 + j];
    }
    __syncthreads();
  }
  #pragma unroll
  for (int j = 0; j < 6; ++j)
    PT[(size_t)(cg * 6 + j) * NODES + node0 + row] = acc[j];
}

// ---------------- readout stage 2 ----------------
__global__ __launch_bounds__(256) void k_readR(const float* __restrict__ PT,
                                               const float* __restrict__ maskR,
                                               const float* __restrict__ bg,
                                               const float* __restrict__ bo,
                                               float* __restrict__ out) {
  __shared__ float red[256];
  const int tid = threadIdx.x;
  const int b = blockIdx.x / TGT_;
  const int t = blockIdx.x - b * TGT_;
  const float bgt = bg[t], bot = bo[t];
  float s = 0.f;
  #pragma unroll
  for (int i = 0; i < 4; ++i) {
    int node = b * N_ + i * 256 + tid;
    float p1 = PT[(size_t)t * NODES + node] + bgt;
    float p2 = PT[(size_t)(12 + t) * NODES + node] + bot;
    s += sigmoidf_(p1) * p2 * maskR[node];
  }
  red[tid] = s;
  __syncthreads();
  #pragma unroll
  for (int off = 128; off > 0; off >>= 1) {
    if (tid < off) red[tid] += red[tid + off];
    __syncthreads();
  }
  if (tid == 0) out[b * TGT_ + t] = red[0];
}

extern "C" void kernel_launch(void* const* d_in, const int* in_sizes, int n_in,
                              void* d_out, int out_size, void* d_ws, size_t ws_size,
                              hipStream_t stream) {
  (void)in_sizes; (void)n_in; (void)out_size; (void)ws_size;
  const float* g    = (const float*)d_in[0];
  const float* h_in = (const float*)d_in[1];
  const int*   e    = (const int*)d_in[2];
  const float* A    = (const float*)d_in[3];
  const float* Wi   = (const float*)d_in[4];
  const float* Wh   = (const float*)d_in[5];
  const float* bi   = (const float*)d_in[6];
  const float* bh   = (const float*)d_in[7];
  const float* Wg   = (const float*)d_in[8];
  const float* bg   = (const float*)d_in[9];
  const float* Wo   = (const float*)d_in[10];
  const float* bo   = (const float*)d_in[11];
  float* out = (float*)d_out;
  float* ws  = (float*)d_ws;

  // workspace layout (~92 MB):
  float* h     = ws;                                   // 1,048,576 f
  float* h0    = h + (size_t)NODES * H_;               // 1,048,576 f
  float* maskA = h0 + (size_t)NODES * H_;              // 8192 f
  float* maskR = maskA + NODES;                        // 8192 f
  float* PT    = maskR + NODES;                        // 196,608 f (readout scratch)
  unsigned short* X    = (unsigned short*)(PT + 24 * NODES);  // 2,097,152 us (h hi|lo)
  unsigned short* ATh  = X + (size_t)NODES * 256;      // 81,920 us
  unsigned short* ATl  = ATh + CAT_ * 128;             // 81,920 us
  unsigned short* WiTh = ATl + CAT_ * 128;             // 49,152 us
  unsigned short* WiTl = WiTh + 384 * 128;             // 49,152 us
  unsigned short* WhTh = WiTl + 384 * 128;             // 49,152 us
  unsigned short* WhTl = WhTh + 384 * 128;             // 49,152 us
  unsigned short* Gb   = WhTl + 384 * 128;             // 8,388,608 us (16.8 MB)
  unsigned char*  Eb   = (unsigned char*)(Gb + (size_t)NODES * N_);   // 8,388,608 u8
  float* aggP = (float*)(Eb + (size_t)NODES * N_);     // KSPLIT * 1,048,576 f (16.8 MB)
  unsigned short* McatT = (unsigned short*)(aggP + (size_t)KSPLIT * NODES * MSG2); // 10.5 MB
  float* gates = (float*)(McatT + (size_t)B_ * L_ * MSG2 * N_);       // 6,291,456 f (25.2 MB)

  k_prep<<<NODES / 4 + (CAT_ * 128) / 256 + (2 * 384 * 128) / 256, 256, 0, stream>>>(
      h_in, A, Wi, Wh, h, h0, X, maskA, maskR, ATh, ATl, WiTh, WiTl, WhTh, WhTl);
  k_pack<<<(NODES * N_ / 8) / 256, 256, 0, stream>>>(g, e, Gb, Eb);
  for (int layer = 0; layer < NLAYERS_; ++layer) {
    k_gemmT<<<dim3(CAT_ / 128, NODES / 64), 256, 0, stream>>>(X, ATh, ATl, McatT);
    k_agg_mfma<<<(N_ / 64) * 2 * KSPLIT * B_, 256, 0, stream>>>(Gb, Eb, McatT, aggP);
    k_gates_mfma<<<dim3(384 / 128, NODES / 64, 2), 256, 0, stream>>>(aggP, X, WiTh, WiTl, WhTh, WhTl, gates);
    k_gru_elt<<<NODES / 8, 256, 0, stream>>>(gates, bi, bh, maskA, h, X,
                                             (layer < NLAYERS_ - 1) ? 1 : 0);
  }
  k_readP<<<NODES / 64, 256, 0, stream>>>(h, h0, Wg, Wo, PT);
  k_readR<<<B_ * TGT_, 256, 0, stream>>>(PT, maskR, bg, bo, out);
}